// Round 1
// baseline (11.735 us; speedup 1.0000x reference)
//
#include <hip/hip_runtime.h>
#include <math.h>

// QCONV1d closed form:
//   ev(b,m,c) = cos(x_flat[3c+1] + w[1]) * cos(x_flat[3c+2] + w[2])
//   where x_flat = x[b, m:m+3, :] (768 contiguous floats)
//   vals[b,m] = sum_c ev ; out[b, m<253, 0..63] = vals ; out[b,253,:] = 0

constexpr int Bn = 32;    // batch
constexpr int Wn = 256;   // width (window dim)
constexpr int Cn = 256;   // channels
constexpr int Mn = 253;   // number of valid windows  (arange(0, W-3))
constexpr int OW = 254;   // out_width = (C - 2 - 1) + 1
constexpr int OF = 64;    // OUT_FILTERS

__global__ __launch_bounds__(256)
void qconv1d_kernel(const float* __restrict__ x,
                    const float* __restrict__ wt,
                    float* __restrict__ out) {
    const int bid = blockIdx.x;          // 0 .. Bn*OW-1
    const int b   = bid / OW;
    const int m   = bid - b * OW;
    const int t   = threadIdx.x;         // 0..255  (one c per thread)

    float* orow = out + ((size_t)b * OW + m) * OF;

    if (m >= Mn) {                       // out row 253: reference leaves zeros
        if (t < OF) orow[t] = 0.0f;
        return;
    }

    const float w1 = wt[1];
    const float w2 = wt[2];

    const float* wf = x + ((size_t)b * Wn + m) * Cn;   // 768 contiguous floats
    const float a1 = wf[3 * t + 1];
    const float a2 = wf[3 * t + 2];
    float v = cosf(a1 + w1) * cosf(a2 + w2);

    // intra-wave butterfly reduce (wave64)
    #pragma unroll
    for (int off = 32; off > 0; off >>= 1)
        v += __shfl_down(v, off, 64);

    __shared__ float parts[4];
    if ((t & 63) == 0) parts[t >> 6] = v;
    __syncthreads();

    if (t < OF) {
        const float total = parts[0] + parts[1] + parts[2] + parts[3];
        orow[t] = total;
    }
}

extern "C" void kernel_launch(void* const* d_in, const int* in_sizes, int n_in,
                              void* d_out, int out_size, void* d_ws, size_t ws_size,
                              hipStream_t stream) {
    const float* x  = (const float*)d_in[0];   // (32, 256, 256) f32
    const float* wt = (const float*)d_in[1];   // (1, 3) f32
    float* out = (float*)d_out;                // (32, 254, 64) f32

    qconv1d_kernel<<<dim3(Bn * OW), dim3(256), 0, stream>>>(x, wt, out);
}

// Round 2
// 10.145 us; speedup vs baseline: 1.1567x; 1.1567x over previous
//
#include <hip/hip_runtime.h>
#include <math.h>

// QCONV1d closed form:
//   vals[b,m] = sum_{c=0}^{255} cos(wf[3c+1]+w[1]) * cos(wf[3c+2]+w[2])
//   wf = x[b, m:m+3, :]  (768 contiguous floats)
//   out[b, m<253, 0..63] = vals ; out[b, 253, :] = 0
//
// Structure: grid = 32 batches x 64 groups; each block stages 6 x-rows (6 KB)
// in LDS, then wave w (of 4) computes window m = 4*g + w. Native __cosf.

constexpr int Bn = 32;    // batch
constexpr int Wn = 256;   // width
constexpr int Cn = 256;   // channels
constexpr int Mn = 253;   // valid windows
constexpr int OW = 254;   // out_width
constexpr int OF = 64;    // OUT_FILTERS
constexpr int MPB = 4;    // windows per block (one per wave)

__global__ __launch_bounds__(256)
void qconv1d_kernel(const float* __restrict__ x,
                    const float* __restrict__ wt,
                    float* __restrict__ out) {
    __shared__ float tile[6 * Cn];      // rows m0 .. m0+5

    const int bid = blockIdx.x;
    const int b   = bid >> 6;           // / 64 groups
    const int g   = bid & 63;
    const int m0  = g * MPB;
    const int t   = threadIdx.x;

    // --- stage 6 rows (1536 floats = 384 float4) coalesced into LDS ---
    const float* xb = x + (size_t)b * Wn * Cn;
    #pragma unroll
    for (int i = t; i < 384; i += 256) {
        int row  = m0 + (i >> 6);                 // 64 float4 per row
        int rowc = row < Wn ? row : Wn - 1;       // clamp (g=63 tail, unused)
        reinterpret_cast<float4*>(tile)[i] =
            reinterpret_cast<const float4*>(xb + (size_t)rowc * Cn)[i & 63];
    }
    __syncthreads();

    const int w    = t >> 6;            // wave id 0..3
    const int lane = t & 63;
    const int m    = m0 + w;
    if (m >= OW) return;                // m = 254,255 in the last group

    float* orow = out + ((size_t)b * OW + m) * OF;
    if (m >= Mn) {                      // m == 253: reference leaves zeros
        orow[lane] = 0.0f;
        return;
    }

    const float w1 = wt[1];
    const float w2 = wt[2];
    const float* wrow = tile + w * Cn;  // window m = rows w..w+2 of tile

    float acc = 0.0f;
    #pragma unroll
    for (int i = 0; i < 4; ++i) {
        const int c = i * 64 + lane;    // lane-stride-1 -> 2-way LDS alias (free)
        const float a1 = wrow[3 * c + 1];
        const float a2 = wrow[3 * c + 2];
        acc += __cosf(a1 + w1) * __cosf(a2 + w2);
    }

    // full-wave butterfly: every lane ends with the total
    #pragma unroll
    for (int off = 32; off > 0; off >>= 1)
        acc += __shfl_xor(acc, off, 64);

    orow[lane] = acc;                   // 64 lanes -> 256 B coalesced store
}

extern "C" void kernel_launch(void* const* d_in, const int* in_sizes, int n_in,
                              void* d_out, int out_size, void* d_ws, size_t ws_size,
                              hipStream_t stream) {
    const float* x  = (const float*)d_in[0];   // (32, 256, 256) f32
    const float* wt = (const float*)d_in[1];   // (1, 3) f32
    float* out = (float*)d_out;                // (32, 254, 64) f32

    qconv1d_kernel<<<dim3(Bn * 64), dim3(256), 0, stream>>>(x, wt, out);
}

// Round 3
// 9.848 us; speedup vs baseline: 1.1916x; 1.0302x over previous
//
#include <hip/hip_runtime.h>
#include <math.h>

// QCONV1d closed form:
//   vals[b,m] = sum_{c=0}^{255} cos(wf[3c+1]+w[1]) * cos(wf[3c+2]+w[2])
//   wf = x[b, m:m+3, :]  (768 contiguous floats)
//   out[b, m<253, 0..63] = vals ; out[b, 253, :] = 0
//
// Structure: grid = 32 batches x 32 groups; 512-thread block stages 10 x-rows
// (10 KB) in LDS, wave w (of 8) computes window m = 8*g + w. Native __cosf.
// 4 blocks/CU x 8 waves = one full-occupancy residency round.

constexpr int Bn  = 32;   // batch
constexpr int Wn  = 256;  // width
constexpr int Cn  = 256;  // channels
constexpr int Mn  = 253;  // valid windows
constexpr int OW  = 254;  // out_width
constexpr int OF  = 64;   // OUT_FILTERS
constexpr int MPB = 8;    // windows per block (one per wave)
constexpr int ROWS = MPB + 2;             // 10 staged rows
constexpr int NV4  = ROWS * Cn / 4;       // 640 float4

__global__ __launch_bounds__(512)
void qconv1d_kernel(const float* __restrict__ x,
                    const float* __restrict__ wt,
                    float* __restrict__ out) {
    __shared__ float tile[ROWS * Cn];

    const int bid = blockIdx.x;
    const int b   = bid >> 5;            // / 32 groups
    const int g   = bid & 31;
    const int m0  = g * MPB;
    const int t   = threadIdx.x;

    // --- stage 10 rows (640 float4) coalesced into LDS ---
    const float* xb = x + (size_t)b * Wn * Cn;
    #pragma unroll
    for (int i = t; i < NV4; i += 512) {
        int row  = m0 + (i >> 6);                 // 64 float4 per row
        int rowc = row < Wn ? row : Wn - 1;       // clamp (last group tail)
        reinterpret_cast<float4*>(tile)[i] =
            reinterpret_cast<const float4*>(xb + (size_t)rowc * Cn)[i & 63];
    }
    __syncthreads();

    const int w    = t >> 6;             // wave id 0..7
    const int lane = t & 63;
    const int m    = m0 + w;
    if (m >= OW) return;                 // m = 254,255 in the last group

    float* orow = out + ((size_t)b * OW + m) * OF;
    if (m >= Mn) {                       // m == 253: reference leaves zeros
        orow[lane] = 0.0f;
        return;
    }

    const float w1 = wt[1];
    const float w2 = wt[2];
    const float* wrow = tile + w * Cn;   // window m = rows w..w+2 of tile

    float acc = 0.0f;
    #pragma unroll
    for (int i = 0; i < 4; ++i) {
        const int c = i * 64 + lane;     // stride-3 word addr -> 2-way alias (free)
        const float a1 = wrow[3 * c + 1];
        const float a2 = wrow[3 * c + 2];
        acc += __cosf(a1 + w1) * __cosf(a2 + w2);
    }

    // full-wave butterfly: every lane ends with the total
    #pragma unroll
    for (int off = 32; off > 0; off >>= 1)
        acc += __shfl_xor(acc, off, 64);

    orow[lane] = acc;                    // 64 lanes -> 256 B coalesced store
}

extern "C" void kernel_launch(void* const* d_in, const int* in_sizes, int n_in,
                              void* d_out, int out_size, void* d_ws, size_t ws_size,
                              hipStream_t stream) {
    const float* x  = (const float*)d_in[0];   // (32, 256, 256) f32
    const float* wt = (const float*)d_in[1];   // (1, 3) f32
    float* out = (float*)d_out;                // (32, 254, 64) f32

    qconv1d_kernel<<<dim3(Bn * 32), dim3(512), 0, stream>>>(x, wt, out);
}